// Round 3
// baseline (191.612 us; speedup 1.0000x reference)
//
#include <hip/hip_runtime.h>

#define B_  8
#define TE_ 256
#define TD_ 128
#define HE_ 512

typedef __attribute__((ext_vector_type(4))) short short4v;
typedef __attribute__((ext_vector_type(8))) short short8v;
typedef __attribute__((ext_vector_type(4))) float f32x4;

__device__ __forceinline__ unsigned short f2bf(float x) {
  union { float f; unsigned u; } v; v.f = x;
  unsigned r = v.u + 0x7fff + ((v.u >> 16) & 1);   // RNE
  return (unsigned short)(r >> 16);
}
__device__ __forceinline__ float bf2f(unsigned short b) {
  union { float f; unsigned u; } v; v.u = ((unsigned)b) << 16;
  return v.f;
}

// tanh(x) = 1 - 2/(exp(2x)+1); 2 transcendentals, err ~1e-6
__device__ __forceinline__ float fast_tanh(float x) {
  float e = __expf(2.0f * x);
  return 1.0f - 2.0f * __builtin_amdgcn_rcpf(e + 1.0f);
}

// ---- conv_a: enc/dec fp32 -> K-concat bf16 [M,1536] = [hi | hi | lo] ----
__global__ __launch_bounds__(256) void conv_a(
    const float* __restrict__ enc, const float* __restrict__ dec,
    short* __restrict__ AE, short* __restrict__ AD) {
  int idx = blockIdx.x * 256 + threadIdx.x;
  const int NE4 = (2048 * 512) / 4;
  const float* src; short* dst;
  if (idx < NE4) { src = enc; dst = AE; }
  else           { idx -= NE4; src = dec; dst = AD; }
  const int m = idx >> 7;            // 128 float4 per 512-row
  const int k = (idx & 127) << 2;
  float4 v = *(const float4*)(src + (size_t)m * 512 + k);
  float vf[4] = {v.x, v.y, v.z, v.w};
  short4v hi, lo;
  for (int j = 0; j < 4; ++j) {
    unsigned short h = f2bf(vf[j]);
    hi[j] = (short)h;
    lo[j] = (short)f2bf(vf[j] - bf2f(h));
  }
  short* base = dst + (size_t)m * 1536 + k;
  *(short4v*)(base)        = hi;
  *(short4v*)(base + 512)  = hi;
  *(short4v*)(base + 1024) = lo;
}

// ---- conv_b: Wa/Ua fp32 [K,N] -> transposed K-concat bf16 BT [N,1536] ----
// Section order [hi | lo | hi] so that with A=[hi|hi|lo]:
//   sum = Ahi*Bhi + Ahi*Blo + Alo*Bhi  (tf32x3-style fp32 emulation)
__global__ __launch_bounds__(256) void conv_b(
    const float* __restrict__ Wa, const float* __restrict__ Ua,
    short* __restrict__ BTW, short* __restrict__ BTU) {
  __shared__ float sT[64][68];
  int bid = blockIdx.x;
  const float* src; short* dst;
  if (bid < 64) { src = Wa; dst = BTW; }
  else          { bid -= 64; src = Ua; dst = BTU; }
  const int kt = (bid >> 3) * 64, nt = (bid & 7) * 64;
  const int tid = threadIdx.x;
  const int lr = tid >> 4;            // 0..15
  const int lc = (tid & 15) * 4;
  for (int i = 0; i < 4; ++i) {
    float4 v = *(const float4*)(src + (size_t)(kt + lr + i * 16) * 512 + nt + lc);
    sT[lr + i * 16][lc + 0] = v.x;
    sT[lr + i * 16][lc + 1] = v.y;
    sT[lr + i * 16][lc + 2] = v.z;
    sT[lr + i * 16][lc + 3] = v.w;
  }
  __syncthreads();
  const int n_l = tid >> 2;
  const int kq  = (tid & 3) * 16;
  short8v hi0, hi1, lo0, lo1;
  for (int j = 0; j < 8; ++j) {
    float x0 = sT[kq + j][n_l];
    float x1 = sT[kq + 8 + j][n_l];
    unsigned short h0 = f2bf(x0), h1 = f2bf(x1);
    hi0[j] = (short)h0; lo0[j] = (short)f2bf(x0 - bf2f(h0));
    hi1[j] = (short)h1; lo1[j] = (short)f2bf(x1 - bf2f(h1));
  }
  short* base = dst + (size_t)(nt + n_l) * 1536 + kt + kq;
  *(short8v*)(base)            = hi0;
  *(short8v*)(base + 8)        = hi1;
  *(short8v*)(base + 512)      = lo0;   // lo section (fixed)
  *(short8v*)(base + 520)      = lo1;
  *(short8v*)(base + 1024)     = hi0;   // hi section (fixed)
  *(short8v*)(base + 1032)     = hi1;
}

// ---- gemm_mfma: C[M,512] = Ahat[M,1536] @ BT[N=512,1536]^T, bf16 MFMA ----
// BM=64, BN=128, BK=32, 256 thr (4 waves), wave quadrant 32x64 = 2x4 MFMA tiles
#define LDK 48
__global__ __launch_bounds__(256) void gemm_mfma(
    const short* __restrict__ AE, const short* __restrict__ AD,
    const short* __restrict__ BTW, const short* __restrict__ BTU,
    float* __restrict__ Ws, float* __restrict__ Uh) {
  __shared__ short sA[64][LDK];
  __shared__ short sB[128][LDK];
  int mt = blockIdx.x;
  const int nt = blockIdx.y;
  const short *Asrc, *Bsrc; float* C;
  if (mt < 32) { Asrc = AE; Bsrc = BTW; C = Ws; }
  else         { mt -= 32; Asrc = AD; Bsrc = BTU; C = Uh; }
  const int m0 = mt * 64, n0 = nt * 128;
  const int tid = threadIdx.x;
  // staging: full BK=32 coverage (R2 bug: only half was written)
  const int arow = tid >> 2, ak = (tid & 3) * 8;    // sA: 64 rows x 4 chunks
  const int brow = tid >> 1, bk = (tid & 1) * 16;   // sB: 128 rows x 2x16
  const int wave = tid >> 6, lane = tid & 63;
  const int wr = (wave >> 1) * 32, wc = (wave & 1) * 64;
  const int fm = lane & 15, fk = (lane >> 4) * 8;
  const int r0 = (lane >> 4) * 4, ccol = lane & 15;
  f32x4 acc[2][4] = {};
  const short* Ap = Asrc + (size_t)(m0 + arow) * 1536 + ak;
  const short* Bp = Bsrc + (size_t)(n0 + brow) * 1536 + bk;
  for (int k0 = 0; k0 < 1536; k0 += 32) {
    short8v av  = *(const short8v*)(Ap + k0);
    short8v bv0 = *(const short8v*)(Bp + k0);
    short8v bv1 = *(const short8v*)(Bp + k0 + 8);
    __syncthreads();
    *(short8v*)&sA[arow][ak]     = av;
    *(short8v*)&sB[brow][bk]     = bv0;
    *(short8v*)&sB[brow][bk + 8] = bv1;
    __syncthreads();
    short8v af[2], bfr[4];
#pragma unroll
    for (int i = 0; i < 2; ++i) af[i] = *(const short8v*)&sA[wr + i * 16 + fm][fk];
#pragma unroll
    for (int j = 0; j < 4; ++j) bfr[j] = *(const short8v*)&sB[wc + j * 16 + fm][fk];
#pragma unroll
    for (int i = 0; i < 2; ++i)
#pragma unroll
      for (int j = 0; j < 4; ++j)
        acc[i][j] = __builtin_amdgcn_mfma_f32_16x16x32_bf16(af[i], bfr[j], acc[i][j], 0, 0, 0);
  }
#pragma unroll
  for (int i = 0; i < 2; ++i)
#pragma unroll
    for (int j = 0; j < 4; ++j) {
      const int row = m0 + wr + i * 16 + r0;
      const int col = n0 + wc + j * 16 + ccol;
#pragma unroll
      for (int r = 0; r < 4; ++r)
        C[(size_t)(row + r) * 512 + col] = acc[i][j][r];
    }
}

// ---- attn_fused: 2 d's per block, grid = 8b x 64 = 512 blocks ----
__global__ __launch_bounds__(256) void attn_fused(
    const float* __restrict__ Ws, const float* __restrict__ Uh,
    const float* __restrict__ Va, const float* __restrict__ enc,
    float* __restrict__ c_out, float* __restrict__ e_out) {
  __shared__ float sUh[2][HE_];
  __shared__ float sV[HE_];
  __shared__ float sE[2][TE_];
  __shared__ float sNorm[2];
  const int tid = threadIdx.x;
  const int b  = blockIdx.x >> 6;
  const int d0 = (blockIdx.x & 63) * 2;
  ((float4*)&sUh[0][0])[tid] = ((const float4*)(Uh + (size_t)(b * TD_ + d0) * HE_))[tid];
  if (tid < 128) ((float4*)sV)[tid] = ((const float4*)Va)[tid];
  __syncthreads();
  const int lane = tid & 63, wave = tid >> 6;
  const int dl = wave & 1, th = wave >> 1;
  const int h0 = lane << 3;
  float uh[8], vv[8];
#pragma unroll
  for (int j = 0; j < 8; ++j) { uh[j] = sUh[dl][h0 + j]; vv[j] = sV[h0 + j]; }
  const float* wsbase = Ws + (size_t)b * TE_ * HE_ + h0;
#pragma unroll 2
  for (int ti = 0; ti < 128; ++ti) {
    const int t = th * 128 + ti;
    const float4 w0 = *(const float4*)(wsbase + (size_t)t * HE_);
    const float4 w1 = *(const float4*)(wsbase + (size_t)t * HE_ + 4);
    float s;
    s  = fast_tanh(w0.x + uh[0]) * vv[0];
    s += fast_tanh(w0.y + uh[1]) * vv[1];
    s += fast_tanh(w0.z + uh[2]) * vv[2];
    s += fast_tanh(w0.w + uh[3]) * vv[3];
    s += fast_tanh(w1.x + uh[4]) * vv[4];
    s += fast_tanh(w1.y + uh[5]) * vv[5];
    s += fast_tanh(w1.z + uh[6]) * vv[6];
    s += fast_tanh(w1.w + uh[7]) * vv[7];
#pragma unroll
    for (int off = 32; off; off >>= 1) s += __shfl_down(s, off, 64);
    if (lane == 0) sE[dl][t] = s;
  }
  __syncthreads();
  // softmax without max-subtraction: |logit| <= sum|V| ~ 23, exp safe in fp32
  if (wave < 2) {
    float ex[4], sum = 0.f;
#pragma unroll
    for (int i = 0; i < 4; ++i) { ex[i] = __expf(sE[wave][i * 64 + lane]); sum += ex[i]; }
#pragma unroll
    for (int i = 0; i < 4; ++i) sE[wave][i * 64 + lane] = ex[i];
#pragma unroll
    for (int off = 32; off; off >>= 1) sum += __shfl_down(sum, off, 64);
    if (lane == 0) sNorm[wave] = 1.0f / sum;
  }
  __syncthreads();
  {
    const int d = tid >> 7, t2 = (tid & 127) * 2;
    const float n = sNorm[d];
    const float e0 = sE[d][t2] * n, e1 = sE[d][t2 + 1] * n;
    sE[d][t2] = e0; sE[d][t2 + 1] = e1;
    float2 eo; eo.x = e0; eo.y = e1;
    *(float2*)(e_out + (size_t)(b * TD_ + d0 + d) * TE_ + t2) = eo;
  }
  __syncthreads();
  const int h2 = tid * 2;
  float a00 = 0.f, a01 = 0.f, a10 = 0.f, a11 = 0.f;
  const float* ep = enc + (size_t)b * TE_ * HE_ + h2;
#pragma unroll 4
  for (int t = 0; t < TE_; ++t) {
    const float2 ev = *(const float2*)(ep + (size_t)t * HE_);
    const float w0 = sE[0][t], w1 = sE[1][t];
    a00 = fmaf(w0, ev.x, a00); a01 = fmaf(w0, ev.y, a01);
    a10 = fmaf(w1, ev.x, a10); a11 = fmaf(w1, ev.y, a11);
  }
  float* cp = c_out + (size_t)(b * TD_ + d0) * HE_ + h2;
  float2 c0; c0.x = a00; c0.y = a01;
  float2 c1; c1.x = a10; c1.y = a11;
  *(float2*)cp = c0;
  *(float2*)(cp + HE_) = c1;
}

extern "C" void kernel_launch(void* const* d_in, const int* in_sizes, int n_in,
                              void* d_out, int out_size, void* d_ws, size_t ws_size,
                              hipStream_t stream) {
  const float* enc = (const float*)d_in[0];   // [8,256,512]
  const float* dec = (const float*)d_in[1];   // [8,128,512]
  const float* Wa  = (const float*)d_in[2];   // [512,512]
  const float* Ua  = (const float*)d_in[3];   // [512,512]
  const float* Va  = (const float*)d_in[4];   // [512,1]
  float* c_out = (float*)d_out;
  float* e_out = c_out + (size_t)B_ * TD_ * HE_;
  char* ws = (char*)d_ws;
  float* Ws  = (float*)(ws);                   // 4 MB
  float* Uh  = (float*)(ws + (4u << 20));      // 2 MB
  short* AE  = (short*)(ws + (6u << 20));      // 6 MB
  short* AD  = (short*)(ws + (12u << 20));     // 3 MB
  short* BTW = (short*)(ws + (15u << 20));     // 1.5 MB
  short* BTU = (short*)(ws + (15u << 20) + (3u << 19)); // 1.5 MB
  conv_a<<<1536, 256, 0, stream>>>(enc, dec, AE, AD);
  conv_b<<<128, 256, 0, stream>>>(Wa, Ua, BTW, BTU);
  gemm_mfma<<<dim3(48, 4), 256, 0, stream>>>(AE, AD, BTW, BTU, Ws, Uh);
  attn_fused<<<512, 256, 0, stream>>>(Ws, Uh, Va, enc, c_out, e_out);
}

// Round 4
// 148.860 us; speedup vs baseline: 1.2872x; 1.2872x over previous
//
#include <hip/hip_runtime.h>

#define B_  8
#define TE_ 256
#define TD_ 128
#define HE_ 512

typedef __attribute__((ext_vector_type(4))) short short4v;
typedef __attribute__((ext_vector_type(8))) short short8v;
typedef __attribute__((ext_vector_type(4))) float f32x4;

__device__ __forceinline__ unsigned short f2bf(float x) {
  union { float f; unsigned u; } v; v.f = x;
  unsigned r = v.u + 0x7fff + ((v.u >> 16) & 1);   // RNE
  return (unsigned short)(r >> 16);
}
__device__ __forceinline__ float bf2f(unsigned short b) {
  union { float f; unsigned u; } v; v.u = ((unsigned)b) << 16;
  return v.f;
}

// tanh(x) = 1 - 2/(exp(2x)+1); 2 transcendentals, err ~1e-6
__device__ __forceinline__ float fast_tanh(float x) {
  float e = __expf(2.0f * x);
  return 1.0f - 2.0f * __builtin_amdgcn_rcpf(e + 1.0f);
}

// ---- conv_all: both operand conversions in one launch ----
// blocks [0,1536): enc/dec -> A-hat [M,1536] = [hi|hi|lo]
// blocks [1536,1664): Wa/Ua -> BT [N,1536] = [hi|lo|hi] (transposed)
__global__ __launch_bounds__(256) void conv_all(
    const float* __restrict__ enc, const float* __restrict__ dec,
    const float* __restrict__ Wa, const float* __restrict__ Ua,
    short* __restrict__ AE, short* __restrict__ AD,
    short* __restrict__ BTW, short* __restrict__ BTU) {
  __shared__ float sT[64][68];
  int bid = blockIdx.x;
  const int tid = threadIdx.x;
  if (bid < 1536) {
    int idx = bid * 256 + tid;
    const int NE4 = (2048 * 512) / 4;
    const float* src; short* dst;
    if (idx < NE4) { src = enc; dst = AE; }
    else           { idx -= NE4; src = dec; dst = AD; }
    const int m = idx >> 7;
    const int k = (idx & 127) << 2;
    float4 v = *(const float4*)(src + (size_t)m * 512 + k);
    float vf[4] = {v.x, v.y, v.z, v.w};
    short4v hi, lo;
    for (int j = 0; j < 4; ++j) {
      unsigned short h = f2bf(vf[j]);
      hi[j] = (short)h;
      lo[j] = (short)f2bf(vf[j] - bf2f(h));
    }
    short* base = dst + (size_t)m * 1536 + k;
    *(short4v*)(base)        = hi;
    *(short4v*)(base + 512)  = hi;
    *(short4v*)(base + 1024) = lo;
    return;
  }
  bid -= 1536;
  const float* src; short* dst;
  if (bid < 64) { src = Wa; dst = BTW; }
  else          { bid -= 64; src = Ua; dst = BTU; }
  const int kt = (bid >> 3) * 64, nt = (bid & 7) * 64;
  const int lr = tid >> 4;
  const int lc = (tid & 15) * 4;
  for (int i = 0; i < 4; ++i) {
    float4 v = *(const float4*)(src + (size_t)(kt + lr + i * 16) * 512 + nt + lc);
    sT[lr + i * 16][lc + 0] = v.x;
    sT[lr + i * 16][lc + 1] = v.y;
    sT[lr + i * 16][lc + 2] = v.z;
    sT[lr + i * 16][lc + 3] = v.w;
  }
  __syncthreads();
  const int n_l = tid >> 2;
  const int kq  = (tid & 3) * 16;
  short8v hi0, hi1, lo0, lo1;
  for (int j = 0; j < 8; ++j) {
    float x0 = sT[kq + j][n_l];
    float x1 = sT[kq + 8 + j][n_l];
    unsigned short h0 = f2bf(x0), h1 = f2bf(x1);
    hi0[j] = (short)h0; lo0[j] = (short)f2bf(x0 - bf2f(h0));
    hi1[j] = (short)h1; lo1[j] = (short)f2bf(x1 - bf2f(h1));
  }
  short* base = dst + (size_t)(nt + n_l) * 1536 + kt + kq;
  *(short8v*)(base)        = hi0;
  *(short8v*)(base + 8)    = hi1;
  *(short8v*)(base + 512)  = lo0;
  *(short8v*)(base + 520)  = lo1;
  *(short8v*)(base + 1024) = hi0;
  *(short8v*)(base + 1032) = hi1;
}

// ---- gemm_mfma: BM=BN=64, BK=64, 256 thr, grid 48x8 = 384 blocks ----
#define LDK 72
__global__ __launch_bounds__(256) void gemm_mfma(
    const short* __restrict__ AE, const short* __restrict__ AD,
    const short* __restrict__ BTW, const short* __restrict__ BTU,
    float* __restrict__ Ws, float* __restrict__ Uh) {
  __shared__ short sA[64][LDK];
  __shared__ short sB[64][LDK];
  int mt = blockIdx.x;
  const int nt = blockIdx.y;
  const short *Asrc, *Bsrc; float* C;
  if (mt < 32) { Asrc = AE; Bsrc = BTW; C = Ws; }
  else         { mt -= 32; Asrc = AD; Bsrc = BTU; C = Uh; }
  const int m0 = mt * 64, n0 = nt * 64;
  const int tid = threadIdx.x;
  const int row = tid >> 2, ck = (tid & 3) * 16;   // staging: 64 rows x 4x16
  const int wave = tid >> 6, lane = tid & 63;
  const int wr = (wave >> 1) * 32, wc = (wave & 1) * 32;
  const int fm = lane & 15, fk = (lane >> 4) * 8;
  const int r0 = (lane >> 4) * 4, ccol = lane & 15;
  f32x4 acc[2][2] = {};
  const short* Ap = Asrc + (size_t)(m0 + row) * 1536 + ck;
  const short* Bp = Bsrc + (size_t)(n0 + row) * 1536 + ck;
  for (int k0 = 0; k0 < 1536; k0 += 64) {
    short8v a0 = *(const short8v*)(Ap + k0);
    short8v a1 = *(const short8v*)(Ap + k0 + 8);
    short8v b0 = *(const short8v*)(Bp + k0);
    short8v b1 = *(const short8v*)(Bp + k0 + 8);
    __syncthreads();
    *(short8v*)&sA[row][ck]     = a0;
    *(short8v*)&sA[row][ck + 8] = a1;
    *(short8v*)&sB[row][ck]     = b0;
    *(short8v*)&sB[row][ck + 8] = b1;
    __syncthreads();
#pragma unroll
    for (int s = 0; s < 64; s += 32) {
      short8v af[2], bfr[2];
#pragma unroll
      for (int i = 0; i < 2; ++i) af[i] = *(const short8v*)&sA[wr + i * 16 + fm][s + fk];
#pragma unroll
      for (int j = 0; j < 2; ++j) bfr[j] = *(const short8v*)&sB[wc + j * 16 + fm][s + fk];
#pragma unroll
      for (int i = 0; i < 2; ++i)
#pragma unroll
        for (int j = 0; j < 2; ++j)
          acc[i][j] = __builtin_amdgcn_mfma_f32_16x16x32_bf16(af[i], bfr[j], acc[i][j], 0, 0, 0);
    }
  }
#pragma unroll
  for (int i = 0; i < 2; ++i)
#pragma unroll
    for (int j = 0; j < 2; ++j) {
      const int crow = m0 + wr + i * 16 + r0;
      const int col  = n0 + wc + j * 16 + ccol;
#pragma unroll
      for (int r = 0; r < 4; ++r)
        C[(size_t)(crow + r) * 512 + col] = acc[i][j][r];
    }
}

// ---- attn_fused: 2 d's per block, 512 threads (8 waves), 512 blocks ----
__global__ __launch_bounds__(512) void attn_fused(
    const float* __restrict__ Ws, const float* __restrict__ Uh,
    const float* __restrict__ Va, const float* __restrict__ enc,
    float* __restrict__ c_out, float* __restrict__ e_out) {
  __shared__ float sUh[2][HE_];
  __shared__ float sV[HE_];
  __shared__ float sE[2][TE_];
  __shared__ float sRed[8];
  __shared__ float sNorm[2];
  const int tid = threadIdx.x;
  const int b  = blockIdx.x >> 6;
  const int d0 = (blockIdx.x & 63) * 2;
  if (tid < 256)
    ((float4*)sUh)[tid] = ((const float4*)(Uh + (size_t)(b * TD_ + d0) * HE_))[tid];
  else if (tid < 384)
    ((float4*)sV)[tid - 256] = ((const float4*)Va)[tid - 256];
  __syncthreads();
  const int lane = tid & 63, wave = tid >> 6;
  const int dl = wave >> 2;           // which d this wave works on
  const int tb = (wave & 3) * 64;     // t-range base
  const int h0 = lane << 3;
  float uh[8], vv[8];
#pragma unroll
  for (int j = 0; j < 8; ++j) { uh[j] = sUh[dl][h0 + j]; vv[j] = sV[h0 + j]; }
  const float* wsbase = Ws + (size_t)b * TE_ * HE_ + h0;
  for (int ti = 0; ti < 64; ti += 2) {
    const int t = tb + ti;
    const float4 wa0 = *(const float4*)(wsbase + (size_t)t * HE_);
    const float4 wa1 = *(const float4*)(wsbase + (size_t)t * HE_ + 4);
    const float4 wb0 = *(const float4*)(wsbase + (size_t)(t + 1) * HE_);
    const float4 wb1 = *(const float4*)(wsbase + (size_t)(t + 1) * HE_ + 4);
    float s0, s1;
    s0  = fast_tanh(wa0.x + uh[0]) * vv[0];
    s1  = fast_tanh(wb0.x + uh[0]) * vv[0];
    s0 += fast_tanh(wa0.y + uh[1]) * vv[1];
    s1 += fast_tanh(wb0.y + uh[1]) * vv[1];
    s0 += fast_tanh(wa0.z + uh[2]) * vv[2];
    s1 += fast_tanh(wb0.z + uh[2]) * vv[2];
    s0 += fast_tanh(wa0.w + uh[3]) * vv[3];
    s1 += fast_tanh(wb0.w + uh[3]) * vv[3];
    s0 += fast_tanh(wa1.x + uh[4]) * vv[4];
    s1 += fast_tanh(wb1.x + uh[4]) * vv[4];
    s0 += fast_tanh(wa1.y + uh[5]) * vv[5];
    s1 += fast_tanh(wb1.y + uh[5]) * vv[5];
    s0 += fast_tanh(wa1.z + uh[6]) * vv[6];
    s1 += fast_tanh(wb1.z + uh[6]) * vv[6];
    s0 += fast_tanh(wa1.w + uh[7]) * vv[7];
    s1 += fast_tanh(wb1.w + uh[7]) * vv[7];
#pragma unroll
    for (int off = 32; off; off >>= 1) {
      s0 += __shfl_down(s0, off, 64);
      s1 += __shfl_down(s1, off, 64);
    }
    if (lane == 0) { sE[dl][t] = s0; sE[dl][t + 1] = s1; }
  }
  __syncthreads();
  // softmax (no max-subtraction: |logit| <= sum|V| ~ 23, exp safe in fp32)
  const int d = tid >> 8, t = tid & 255;
  const float ex = __expf(sE[d][t]);
  float sum = ex;
#pragma unroll
  for (int off = 32; off; off >>= 1) sum += __shfl_down(sum, off, 64);
  if (lane == 0) sRed[wave] = sum;
  __syncthreads();
  if (tid < 2)
    sNorm[tid] = 1.0f / (sRed[tid * 4] + sRed[tid * 4 + 1] + sRed[tid * 4 + 2] + sRed[tid * 4 + 3]);
  __syncthreads();
  const float wgt = ex * sNorm[d];
  sE[d][t] = wgt;
  e_out[(size_t)(b * TD_ + d0 + d) * TE_ + t] = wgt;
  __syncthreads();
  // phase 3: c[b,d0+{0,1},h] ; thread owns h = tid
  float a0 = 0.f, a1 = 0.f;
  const float* ep = enc + (size_t)b * TE_ * HE_ + tid;
#pragma unroll 4
  for (int tt = 0; tt < TE_; ++tt) {
    const float ev = ep[(size_t)tt * HE_];
    a0 = fmaf(sE[0][tt], ev, a0);
    a1 = fmaf(sE[1][tt], ev, a1);
  }
  float* cp = c_out + (size_t)(b * TD_ + d0) * HE_ + tid;
  cp[0]   = a0;
  cp[HE_] = a1;
}

extern "C" void kernel_launch(void* const* d_in, const int* in_sizes, int n_in,
                              void* d_out, int out_size, void* d_ws, size_t ws_size,
                              hipStream_t stream) {
  const float* enc = (const float*)d_in[0];   // [8,256,512]
  const float* dec = (const float*)d_in[1];   // [8,128,512]
  const float* Wa  = (const float*)d_in[2];   // [512,512]
  const float* Ua  = (const float*)d_in[3];   // [512,512]
  const float* Va  = (const float*)d_in[4];   // [512,1]
  float* c_out = (float*)d_out;
  float* e_out = c_out + (size_t)B_ * TD_ * HE_;
  char* ws = (char*)d_ws;
  float* Ws  = (float*)(ws);                   // 4 MB
  float* Uh  = (float*)(ws + (4u << 20));      // 2 MB
  short* AE  = (short*)(ws + (6u << 20));      // 6 MB
  short* AD  = (short*)(ws + (12u << 20));     // 3 MB
  short* BTW = (short*)(ws + (15u << 20));     // 1.5 MB
  short* BTU = (short*)(ws + (15u << 20) + (3u << 19)); // 1.5 MB
  conv_all<<<1664, 256, 0, stream>>>(enc, dec, Wa, Ua, AE, AD, BTW, BTU);
  gemm_mfma<<<dim3(48, 8), 256, 0, stream>>>(AE, AD, BTW, BTU, Ws, Uh);
  attn_fused<<<512, 512, 0, stream>>>(Ws, Uh, Va, enc, c_out, e_out);
}